// Round 12
// baseline (323.515 us; speedup 1.0000x reference)
//
#include <hip/hip_runtime.h>
#include <math.h>

#define NB 8
#define NH 3
#define NBH 24
#define NP 4096
#define BLK 256
#define RPB 128            // rows per block (4 waves x 32)
#define ROWBLKS (NP / RPB) // 32

typedef _Float16 half8 __attribute__((ext_vector_type(8)));
typedef float floatx16 __attribute__((ext_vector_type(16)));

// Forced v_min3_f32 (3-input min; no -ffast-math so compiler won't fuse).
#define MIN3(r, a, b) asm("v_min3_f32 %0, %0, %1, %2" : "+v"(r) : "v"(a), "v"(b))

// Native gfx950 x16 MFMA via inline asm, all-VGPR operands.
#define MFMA16(d, a, bb, c) \
    asm("v_mfma_f32_32x32x16_f16 %0, %1, %2, %3" : "=&v"(d) : "v"(a), "v"(bb), "v"(c))

// R11 post-mortem: VGPR_Count=64 == exactly the 4x16 MFMA dest regs — the RA
// parked rm/crsq/afrag in AGPR *homes* and satisfied every "v" constraint with
// v_accvgpr_read/write copies (3 instrs per min3 -> the stubborn 3x VALU
// bloat, R6-R11's ~38us plateau). This fence clobbers a0-a191 inside the hot
// loop: AGPR homes become impossible, so all loop-carried values get VGPR
// homes (~130 live < 170 budget at 3 waves/EU -> no spill).
#define AGPR_FENCE() asm volatile("" ::: \
    "a0","a1","a2","a3","a4","a5","a6","a7","a8","a9","a10","a11","a12","a13","a14","a15", \
    "a16","a17","a18","a19","a20","a21","a22","a23","a24","a25","a26","a27","a28","a29","a30","a31", \
    "a32","a33","a34","a35","a36","a37","a38","a39","a40","a41","a42","a43","a44","a45","a46","a47", \
    "a48","a49","a50","a51","a52","a53","a54","a55","a56","a57","a58","a59","a60","a61","a62","a63", \
    "a64","a65","a66","a67","a68","a69","a70","a71","a72","a73","a74","a75","a76","a77","a78","a79", \
    "a80","a81","a82","a83","a84","a85","a86","a87","a88","a89","a90","a91","a92","a93","a94","a95", \
    "a96","a97","a98","a99","a100","a101","a102","a103","a104","a105","a106","a107","a108","a109","a110","a111", \
    "a112","a113","a114","a115","a116","a117","a118","a119","a120","a121","a122","a123","a124","a125","a126","a127", \
    "a128","a129","a130","a131","a132","a133","a134","a135","a136","a137","a138","a139","a140","a141","a142","a143", \
    "a144","a145","a146","a147","a148","a149","a150","a151","a152","a153","a154","a155","a156","a157","a158","a159", \
    "a160","a161","a162","a163","a164","a165","a166","a167","a168","a169","a170","a171","a172","a173","a174","a175", \
    "a176","a177","a178","a179","a180","a181","a182","a183","a184","a185","a186","a187","a188","a189","a190","a191")

// out[0] = 25 * sum_b || N_b N_b^T - I ||_F  (plain store; runs before chamfer adds)
__global__ void reg_kernel(const float* __restrict__ planes, float* __restrict__ out) {
    const int l = threadIdx.x;
    float r = 0.0f;
    if (l < NB) {
        float n[NH][3];
        for (int hh = 0; hh < NH; ++hh) {
            const float* pl = planes + (l * NH + hh) * 4;
            float a0 = pl[0], a1 = pl[1], a2 = pl[2];
            float inv = 1.0f / sqrtf(a0 * a0 + a1 * a1 + a2 * a2);
            n[hh][0] = a0 * inv; n[hh][1] = a1 * inv; n[hh][2] = a2 * inv;
        }
        float fro = 0.0f;
        for (int i = 0; i < NH; ++i)
            for (int j = 0; j < NH; ++j) {
                float d = n[i][0] * n[j][0] + n[i][1] * n[j][1] + n[i][2] * n[j][2]
                          - (i == j ? 1.0f : 0.0f);
                fro += d * d;
            }
        r = 25.0f * sqrtf(fro);
    }
    for (int o = 32; o; o >>= 1) r += __shfl_down(r, o);
    if (l == 0) out[0] = r;
}

// Native 32x32x16: B = RAW ds_read_b128 payload = two packed columns
// (k=0..3 even col, k=4..7 odd col of a 64-col supertile). A_even holds
// [r0,r1,r2,1] in k=0..3 (zeros k=4..7), A_odd the reverse — each MFMA's
// A-zeros annihilate the other packed column. C = rsq(row) -> D = full
// squared distance; clamp after min (exact); block-reduce; 1 atomic/block.
__global__ void __launch_bounds__(BLK, 3) chamfer_mfma(const float* __restrict__ pts,
                                                       const float* __restrict__ planes,
                                                       float* __restrict__ out) {
    __shared__ _Float16 qcols[NP * 4];   // 32 KB: per col [-2c0,-2c1,-2c2,csq]
    __shared__ float rsqbuf[RPB];
    __shared__ float bsum[4];

    const int tid  = threadIdx.x;
    const int lane = tid & 63;
    const int wave = tid >> 6;
    const int bh   = blockIdx.y;
    const int b    = bh / NH;

    const float* pl = planes + bh * 4;
    float n0 = pl[0], n1 = pl[1], n2 = pl[2], off = pl[3];
    float inv = 1.0f / sqrtf(n0 * n0 + n1 * n1 + n2 * n2);
    n0 *= inv; n1 *= inv; n2 *= inv;

    const float* bp = pts + (size_t)b * NP * 3;
    const int h = lane >> 5;

    float total = 0.0f;

    for (int dir = 0; dir < 2; ++dir) {
        // stage 4096 cols (reflected when dir==0)
        for (int i = tid; i < NP; i += BLK) {
            float y0 = bp[i * 3 + 0], y1 = bp[i * 3 + 1], y2 = bp[i * 3 + 2];
            if (!dir) { float t = 2.0f * (n0 * y0 + n1 * y1 + n2 * y2 + off); y0 -= t * n0; y1 -= t * n1; y2 -= t * n2; }
            float csq = y0 * y0 + y1 * y1 + y2 * y2;
            _Float16* q = &qcols[i * 4];
            q[0] = (_Float16)(-2.0f * y0); q[1] = (_Float16)(-2.0f * y1);
            q[2] = (_Float16)(-2.0f * y2); q[3] = (_Float16)csq;
        }

        // A fragments: lane m = lane&31; only lanes<32 carry data.
        const int rlocal = wave * 32 + (lane & 31);
        const int row = blockIdx.x * RPB + rlocal;
        half8 Aev = {0, 0, 0, 0, 0, 0, 0, 0};
        half8 Aod = {0, 0, 0, 0, 0, 0, 0, 0};
        {
            float a0 = bp[row * 3 + 0], a1 = bp[row * 3 + 1], a2 = bp[row * 3 + 2];
            if (dir) { float t = 2.0f * (n0 * a0 + n1 * a1 + n2 * a2 + off); a0 -= t * n0; a1 -= t * n1; a2 -= t * n2; }
            if (lane < 32) {
                rsqbuf[rlocal] = a0 * a0 + a1 * a1 + a2 * a2;
                Aev[0] = (_Float16)a0; Aev[1] = (_Float16)a1;
                Aev[2] = (_Float16)a2; Aev[3] = (_Float16)1.0f;
                Aod[4] = (_Float16)a0; Aod[5] = (_Float16)a1;
                Aod[6] = (_Float16)a2; Aod[7] = (_Float16)1.0f;
            }
        }
        __syncthreads();

        // C fragment: rsq per output row (C/D: col=lane&31, row=(j&3)+8*(j>>2)+4*h)
        floatx16 crsq;
        #pragma unroll
        for (int j = 0; j < 16; ++j)
            crsq[j] = rsqbuf[wave * 32 + (j & 3) + 8 * (j >> 2) + 4 * h];

        float rm[16];
        #pragma unroll
        for (int j = 0; j < 16; ++j) rm[j] = 1e30f;

        // supertile u (64 cols): lane reads cols u*64 + {2l, 2l+1} as one b128
        const _Float16* bcol = &qcols[(lane & 31) * 8];
        #define LD(u) (*(const half8*)(bcol + (u) * 256))

        half8 c0 = LD(0), c1 = LD(1), c2 = LD(2), c3 = LD(3);
        floatx16 dA0, dA1, dB0, dB1;
        MFMA16(dA0, Aev, c0, crsq);  MFMA16(dA1, Aod, c0, crsq);   // st 0
        MFMA16(dB0, Aev, c1, crsq);  MFMA16(dB1, Aod, c1, crsq);   // st 1

        #pragma unroll 1
        for (int u = 4; u <= 60; u += 4) {
            AGPR_FENCE();   // no AGPR homes for any loop-carried value
            c0 = LD(u);
            #pragma unroll
            for (int j = 0; j < 16; ++j) MIN3(rm[j], dA0[j], dA1[j]);   // st u-4
            MFMA16(dA0, Aev, c2, crsq);  MFMA16(dA1, Aod, c2, crsq);    // st u-2
            c1 = LD(u + 1);
            #pragma unroll
            for (int j = 0; j < 16; ++j) MIN3(rm[j], dB0[j], dB1[j]);   // st u-3
            MFMA16(dB0, Aev, c3, crsq);  MFMA16(dB1, Aod, c3, crsq);    // st u-1
            c2 = LD(u + 2);
            #pragma unroll
            for (int j = 0; j < 16; ++j) MIN3(rm[j], dA0[j], dA1[j]);   // st u-2
            MFMA16(dA0, Aev, c0, crsq);  MFMA16(dA1, Aod, c0, crsq);    // st u
            c3 = LD(u + 3);
            #pragma unroll
            for (int j = 0; j < 16; ++j) MIN3(rm[j], dB0[j], dB1[j]);   // st u-1
            MFMA16(dB0, Aev, c1, crsq);  MFMA16(dB1, Aod, c1, crsq);    // st u+1
        }
        {   // epilogue: st 62, 63 issue + drain (st 60..63 consumed here)
            AGPR_FENCE();
            #pragma unroll
            for (int j = 0; j < 16; ++j) MIN3(rm[j], dA0[j], dA1[j]);   // st 60
            MFMA16(dA0, Aev, c2, crsq);  MFMA16(dA1, Aod, c2, crsq);    // st 62
            #pragma unroll
            for (int j = 0; j < 16; ++j) MIN3(rm[j], dB0[j], dB1[j]);   // st 61
            MFMA16(dB0, Aev, c3, crsq);  MFMA16(dB1, Aod, c3, crsq);    // st 63
            #pragma unroll
            for (int j = 0; j < 16; ++j) MIN3(rm[j], dA0[j], dA1[j]);   // st 62
            #pragma unroll
            for (int j = 0; j < 16; ++j) MIN3(rm[j], dB0[j], dB1[j]);   // st 63
        }
        #undef LD

        // min across the 32 lanes sharing each row, then clamp + sum
        #pragma unroll
        for (int j = 0; j < 16; ++j) {
            float v = rm[j];
            v = fminf(v, __shfl_xor(v, 1));
            v = fminf(v, __shfl_xor(v, 2));
            v = fminf(v, __shfl_xor(v, 4));
            v = fminf(v, __shfl_xor(v, 8));
            v = fminf(v, __shfl_xor(v, 16));
            rm[j] = v;
        }
        float s = 0.0f;
        #pragma unroll
        for (int j = 0; j < 16; ++j) s += fmaxf(rm[j], 0.0f);  // clamp after min
        s += __shfl_xor(s, 32);   // combine the two 16-row halves of the wave
        total += s;

        __syncthreads();   // qcols/rsqbuf safe to overwrite for next dir
    }

    if (lane == 0) bsum[wave] = total;
    __syncthreads();
    if (tid == 0)
        atomicAdd(out, (bsum[0] + bsum[1] + bsum[2] + bsum[3]) * (1.0f / (float)(NB * NP)));
}

extern "C" void kernel_launch(void* const* d_in, const int* in_sizes, int n_in,
                              void* d_out, int out_size, void* d_ws, size_t ws_size,
                              hipStream_t stream) {
    const float* planes = (const float*)d_in[0];  // (8,3,4) fp32
    const float* pts    = (const float*)d_in[1];  // (8,4096,3) fp32
    float* out          = (float*)d_out;

    reg_kernel<<<1, 64, 0, stream>>>(planes, out);   // initializes out[0]

    dim3 grid(ROWBLKS, NBH);
    chamfer_mfma<<<grid, BLK, 0, stream>>>(pts, planes, out);
}

// Round 13
// 91.713 us; speedup vs baseline: 3.5275x; 3.5275x over previous
//
#include <hip/hip_runtime.h>
#include <math.h>

#define NB 8
#define NH 3
#define NBH 24
#define NP 4096
#define BLK 256
#define RPB 128            // rows per block (4 waves x 32)
#define ROWBLKS (NP / RPB) // 32

typedef _Float16 half8 __attribute__((ext_vector_type(8)));
typedef float floatx16 __attribute__((ext_vector_type(16)));

// Forced v_min3_f32 (3-input min; no -ffast-math so compiler won't fuse).
#define MIN3(r, a, b) asm("v_min3_f32 %0, %0, %1, %2" : "+v"(r) : "v"(a), "v"(b))

// Native gfx950 x16 MFMA via inline asm, all-VGPR operands (VGPR-form MFMA).
#define MFMA16(d, a, bb, c) \
    asm("v_mfma_f32_32x32x16_f16 %0, %1, %2, %3" : "=&v"(d) : "v"(a), "v"(bb), "v"(c))

// out[0] = 25 * sum_b || N_b N_b^T - I ||_F  (plain store; runs before chamfer adds)
__global__ void reg_kernel(const float* __restrict__ planes, float* __restrict__ out) {
    const int l = threadIdx.x;
    float r = 0.0f;
    if (l < NB) {
        float n[NH][3];
        for (int hh = 0; hh < NH; ++hh) {
            const float* pl = planes + (l * NH + hh) * 4;
            float a0 = pl[0], a1 = pl[1], a2 = pl[2];
            float inv = 1.0f / sqrtf(a0 * a0 + a1 * a1 + a2 * a2);
            n[hh][0] = a0 * inv; n[hh][1] = a1 * inv; n[hh][2] = a2 * inv;
        }
        float fro = 0.0f;
        for (int i = 0; i < NH; ++i)
            for (int j = 0; j < NH; ++j) {
                float d = n[i][0] * n[j][0] + n[i][1] * n[j][1] + n[i][2] * n[j][2]
                          - (i == j ? 1.0f : 0.0f);
                fro += d * d;
            }
        r = 25.0f * sqrtf(fro);
    }
    for (int o = 32; o; o >>= 1) r += __shfl_down(r, o);
    if (l == 0) out[0] = r;
}

// Native 32x32x16: B = RAW ds_read_b128 payload = two packed columns
// (k=0..3 even col, k=4..7 odd col of a 64-col supertile). A_even holds
// [r0,r1,r2,1] in k=0..3 (zeros k=4..7), A_odd the reverse — each MFMA's
// A-zeros annihilate the other packed column. C = rsq(row) -> D = full
// squared distance; clamp after min (exact); block-reduce; 1 atomic/block.
//
// __launch_bounds__(256,2): R12's fence-spill experiment measured true
// VGPR-only demand ~175+ regs — OVER the 170 budget of waves=3, which is
// why R6-R11's RA was FORCED to park rm/crsq/A in AGPRs and pay
// v_accvgpr_read/write per min3 (the ~39us plateau). 256-reg budget fits
// the whole working set in VGPRs; 2 blocks/CU resident is the price.
__global__ void __launch_bounds__(BLK, 2) chamfer_mfma(const float* __restrict__ pts,
                                                       const float* __restrict__ planes,
                                                       float* __restrict__ out) {
    __shared__ _Float16 qcols[NP * 4];   // 32 KB: per col [-2c0,-2c1,-2c2,csq]
    __shared__ float rsqbuf[RPB];
    __shared__ float bsum[4];

    const int tid  = threadIdx.x;
    const int lane = tid & 63;
    const int wave = tid >> 6;
    const int bh   = blockIdx.y;
    const int b    = bh / NH;

    const float* pl = planes + bh * 4;
    float n0 = pl[0], n1 = pl[1], n2 = pl[2], off = pl[3];
    float inv = 1.0f / sqrtf(n0 * n0 + n1 * n1 + n2 * n2);
    n0 *= inv; n1 *= inv; n2 *= inv;

    const float* bp = pts + (size_t)b * NP * 3;
    const int h = lane >> 5;

    float total = 0.0f;

    for (int dir = 0; dir < 2; ++dir) {
        // stage 4096 cols (reflected when dir==0)
        for (int i = tid; i < NP; i += BLK) {
            float y0 = bp[i * 3 + 0], y1 = bp[i * 3 + 1], y2 = bp[i * 3 + 2];
            if (!dir) { float t = 2.0f * (n0 * y0 + n1 * y1 + n2 * y2 + off); y0 -= t * n0; y1 -= t * n1; y2 -= t * n2; }
            float csq = y0 * y0 + y1 * y1 + y2 * y2;
            _Float16* q = &qcols[i * 4];
            q[0] = (_Float16)(-2.0f * y0); q[1] = (_Float16)(-2.0f * y1);
            q[2] = (_Float16)(-2.0f * y2); q[3] = (_Float16)csq;
        }

        // A fragments: lane m = lane&31; only lanes<32 carry data.
        const int rlocal = wave * 32 + (lane & 31);
        const int row = blockIdx.x * RPB + rlocal;
        half8 Aev = {0, 0, 0, 0, 0, 0, 0, 0};
        half8 Aod = {0, 0, 0, 0, 0, 0, 0, 0};
        {
            float a0 = bp[row * 3 + 0], a1 = bp[row * 3 + 1], a2 = bp[row * 3 + 2];
            if (dir) { float t = 2.0f * (n0 * a0 + n1 * a1 + n2 * a2 + off); a0 -= t * n0; a1 -= t * n1; a2 -= t * n2; }
            if (lane < 32) {
                rsqbuf[rlocal] = a0 * a0 + a1 * a1 + a2 * a2;
                Aev[0] = (_Float16)a0; Aev[1] = (_Float16)a1;
                Aev[2] = (_Float16)a2; Aev[3] = (_Float16)1.0f;
                Aod[4] = (_Float16)a0; Aod[5] = (_Float16)a1;
                Aod[6] = (_Float16)a2; Aod[7] = (_Float16)1.0f;
            }
        }
        __syncthreads();

        // C fragment: rsq per output row (C/D: col=lane&31, row=(j&3)+8*(j>>2)+4*h)
        floatx16 crsq;
        #pragma unroll
        for (int j = 0; j < 16; ++j)
            crsq[j] = rsqbuf[wave * 32 + (j & 3) + 8 * (j >> 2) + 4 * h];

        float rm[16];
        #pragma unroll
        for (int j = 0; j < 16; ++j) rm[j] = 1e30f;

        // supertile u (64 cols): lane reads cols u*64 + {2l, 2l+1} as one b128
        const _Float16* bcol = &qcols[(lane & 31) * 8];
        #define LD(u) (*(const half8*)(bcol + (u) * 256))

        half8 c0 = LD(0), c1 = LD(1), c2 = LD(2), c3 = LD(3);
        floatx16 dA0, dA1, dB0, dB1;
        MFMA16(dA0, Aev, c0, crsq);  MFMA16(dA1, Aod, c0, crsq);   // st 0
        MFMA16(dB0, Aev, c1, crsq);  MFMA16(dB1, Aod, c1, crsq);   // st 1

        #pragma unroll 1
        for (int u = 4; u <= 60; u += 4) {
            c0 = LD(u);
            #pragma unroll
            for (int j = 0; j < 16; ++j) MIN3(rm[j], dA0[j], dA1[j]);   // st u-4
            MFMA16(dA0, Aev, c2, crsq);  MFMA16(dA1, Aod, c2, crsq);    // st u-2
            c1 = LD(u + 1);
            #pragma unroll
            for (int j = 0; j < 16; ++j) MIN3(rm[j], dB0[j], dB1[j]);   // st u-3
            MFMA16(dB0, Aev, c3, crsq);  MFMA16(dB1, Aod, c3, crsq);    // st u-1
            c2 = LD(u + 2);
            #pragma unroll
            for (int j = 0; j < 16; ++j) MIN3(rm[j], dA0[j], dA1[j]);   // st u-2
            MFMA16(dA0, Aev, c0, crsq);  MFMA16(dA1, Aod, c0, crsq);    // st u
            c3 = LD(u + 3);
            #pragma unroll
            for (int j = 0; j < 16; ++j) MIN3(rm[j], dB0[j], dB1[j]);   // st u-1
            MFMA16(dB0, Aev, c1, crsq);  MFMA16(dB1, Aod, c1, crsq);    // st u+1
        }
        {   // epilogue: st 62, 63 issue + drain (st 60..63 consumed here)
            #pragma unroll
            for (int j = 0; j < 16; ++j) MIN3(rm[j], dA0[j], dA1[j]);   // st 60
            MFMA16(dA0, Aev, c2, crsq);  MFMA16(dA1, Aod, c2, crsq);    // st 62
            #pragma unroll
            for (int j = 0; j < 16; ++j) MIN3(rm[j], dB0[j], dB1[j]);   // st 61
            MFMA16(dB0, Aev, c3, crsq);  MFMA16(dB1, Aod, c3, crsq);    // st 63
            #pragma unroll
            for (int j = 0; j < 16; ++j) MIN3(rm[j], dA0[j], dA1[j]);   // st 62
            #pragma unroll
            for (int j = 0; j < 16; ++j) MIN3(rm[j], dB0[j], dB1[j]);   // st 63
        }
        #undef LD

        // min across the 32 lanes sharing each row, then clamp + sum
        #pragma unroll
        for (int j = 0; j < 16; ++j) {
            float v = rm[j];
            v = fminf(v, __shfl_xor(v, 1));
            v = fminf(v, __shfl_xor(v, 2));
            v = fminf(v, __shfl_xor(v, 4));
            v = fminf(v, __shfl_xor(v, 8));
            v = fminf(v, __shfl_xor(v, 16));
            rm[j] = v;
        }
        float s = 0.0f;
        #pragma unroll
        for (int j = 0; j < 16; ++j) s += fmaxf(rm[j], 0.0f);  // clamp after min
        s += __shfl_xor(s, 32);   // combine the two 16-row halves of the wave
        total += s;

        __syncthreads();   // qcols/rsqbuf safe to overwrite for next dir
    }

    if (lane == 0) bsum[wave] = total;
    __syncthreads();
    if (tid == 0)
        atomicAdd(out, (bsum[0] + bsum[1] + bsum[2] + bsum[3]) * (1.0f / (float)(NB * NP)));
}

extern "C" void kernel_launch(void* const* d_in, const int* in_sizes, int n_in,
                              void* d_out, int out_size, void* d_ws, size_t ws_size,
                              hipStream_t stream) {
    const float* planes = (const float*)d_in[0];  // (8,3,4) fp32
    const float* pts    = (const float*)d_in[1];  // (8,4096,3) fp32
    float* out          = (float*)d_out;

    reg_kernel<<<1, 64, 0, stream>>>(planes, out);   // initializes out[0]

    dim3 grid(ROWBLKS, NBH);
    chamfer_mfma<<<grid, BLK, 0, stream>>>(pts, planes, out);
}